// Round 1
// baseline (3522.902 us; speedup 1.0000x reference)
//
#include <hip/hip_runtime.h>
#include <hip/hip_bf16.h>
#include <cstdint>

#define NN 100000
#define DD 128
#define EE 1000000
#define KT 384
#define BN_EPS 1e-5f

typedef __attribute__((ext_vector_type(4))) float f32x4;
typedef __attribute__((ext_vector_type(8))) short bf16x8;
typedef __attribute__((ext_vector_type(4))) unsigned short u16x4;
typedef __attribute__((ext_vector_type(8))) unsigned short u16x8;

__device__ __forceinline__ unsigned short f2bf(float f) {
  union { float f; unsigned u; } c; c.f = f;
  unsigned u = c.u;
  return (unsigned short)((u + 0x7FFFu + ((u >> 16) & 1u)) >> 16);  // RNE
}

// ---------------------------------------------------------------- scatter
// one edge per 32 threads; each thread handles 4 features (float4 gather,
// 4 scalar f32 atomics). grid covers exactly 2*EE edges.
__global__ __launch_bounds__(256) void scatter_k(
    const float* __restrict__ x, const int* __restrict__ lei,
    const int* __restrict__ gei, float* __restrict__ aggL,
    float* __restrict__ aggG) {
  long long gt = (long long)blockIdx.x * 256 + threadIdx.x;
  long long eg = gt >> 5;
  int f = (int)(gt & 31);
  const int* ei; float* agg; int e;
  if (eg < EE) { ei = lei; agg = aggL; e = (int)eg; }
  else         { ei = gei; agg = aggG; e = (int)(eg - EE); }
  int row = ei[e];
  int col = ei[EE + e];
  f32x4 v = *(const f32x4*)(x + (size_t)col * DD + f * 4);
  float* dst = agg + (size_t)row * DD + f * 4;
  atomicAdd(dst + 0, v[0]);
  atomicAdd(dst + 1, v[1]);
  atomicAdd(dst + 2, v[2]);
  atomicAdd(dst + 3, v[3]);
}

// ---------------------------------------------------------------- pack B
// B[j][k] (row-major, 128x384 bf16): k<128 -> W1[j][k], <256 -> W2L, else W2G
__global__ __launch_bounds__(256) void packB_k(
    const float* __restrict__ W1, const float* __restrict__ W2L,
    const float* __restrict__ W2G, unsigned short* __restrict__ Bw) {
  int t = blockIdx.x * 256 + threadIdx.x;  // < 128*384 = 49152
  int j = t / KT, k = t - j * KT;
  const float* W = (k < DD) ? W1 : ((k < 2 * DD) ? W2L : W2G);
  Bw[t] = f2bf(W[j * DD + (k & (DD - 1))]);
}

// ---------------------------------------------------------------- GEMM
// out[N,128] = [x | aggL | aggG] (K=384, bf16) @ B[384,128]
// 128x128 tile, 4 waves, 16x16x32 MFMA; epilogue: store + BN col-stats atomics
__global__ __launch_bounds__(256) void gemm_k(
    const float* __restrict__ x, const float* __restrict__ aggL,
    const float* __restrict__ aggG, const unsigned short* __restrict__ Bw,
    float* __restrict__ out, float* __restrict__ stats) {
  __shared__ unsigned short Asm[128 * 32];  // [m][k] bf16
  __shared__ unsigned short Bsm[128 * 32];  // [n][k] bf16
  int t = threadIdx.x;
  int wave = t >> 6, lane = t & 63;
  int row0 = blockIdx.x * 128;

  f32x4 acc[2][8];
#pragma unroll
  for (int mi = 0; mi < 2; ++mi)
#pragma unroll
    for (int ni = 0; ni < 8; ++ni) acc[mi][ni] = (f32x4){0.f, 0.f, 0.f, 0.f};

  for (int step = 0; step < 12; ++step) {
    const float* Asrc = (step < 4) ? x : ((step < 8) ? aggL : aggG);
    int c0 = (step & 3) * 32;
    int k0 = step * 32;
    // stage A (f32 -> bf16), 128 rows x 32 k
#pragma unroll
    for (int i = 0; i < 4; ++i) {
      int flat = t + i * 256;           // 1024 float4 units
      int r = flat >> 3, kq = flat & 7;
      f32x4 v = (f32x4){0.f, 0.f, 0.f, 0.f};
      if (row0 + r < NN)
        v = *(const f32x4*)(Asrc + (size_t)(row0 + r) * DD + c0 + kq * 4);
      u16x4 h;
      h[0] = f2bf(v[0]); h[1] = f2bf(v[1]); h[2] = f2bf(v[2]); h[3] = f2bf(v[3]);
      *(u16x4*)(&Asm[r * 32 + kq * 4]) = h;  // ds_write_b64, linear
    }
    // stage B (already bf16)
#pragma unroll
    for (int i = 0; i < 2; ++i) {
      int flat = t + i * 256;           // 512 x 16B units
      int r = flat >> 2, kq8 = flat & 3;
      u16x8 w = *(const u16x8*)(Bw + (size_t)r * KT + k0 + kq8 * 8);
      *(u16x8*)(&Bsm[r * 32 + kq8 * 8]) = w;
    }
    __syncthreads();
    int mrow = lane & 15, kg = (lane >> 4) * 8;
    bf16x8 a0 = *(const bf16x8*)(&Asm[(wave * 32 + mrow) * 32 + kg]);
    bf16x8 a1 = *(const bf16x8*)(&Asm[(wave * 32 + 16 + mrow) * 32 + kg]);
#pragma unroll
    for (int ni = 0; ni < 8; ++ni) {
      bf16x8 b = *(const bf16x8*)(&Bsm[(ni * 16 + mrow) * 32 + kg]);
      acc[0][ni] = __builtin_amdgcn_mfma_f32_16x16x32_bf16(a0, b, acc[0][ni], 0, 0, 0);
      acc[1][ni] = __builtin_amdgcn_mfma_f32_16x16x32_bf16(a1, b, acc[1][ni], 0, 0, 0);
    }
    __syncthreads();
  }

  // epilogue: C/D layout col=lane&15, row=(lane>>4)*4+reg  [m89-verified]
  int colbase = lane & 15;
  int rbase = (lane >> 4) * 4;
#pragma unroll
  for (int ni = 0; ni < 8; ++ni) {
    int col = ni * 16 + colbase;
    float s = 0.f, q = 0.f;
#pragma unroll
    for (int mi = 0; mi < 2; ++mi) {
#pragma unroll
      for (int r = 0; r < 4; ++r) {
        int row = row0 + wave * 32 + mi * 16 + rbase + r;
        float v = acc[mi][ni][r];
        if (row < NN) {
          out[(size_t)row * DD + col] = v;
          s += v; q += v * v;
        }
      }
    }
    s += __shfl_xor(s, 16); s += __shfl_xor(s, 32);
    q += __shfl_xor(q, 16); q += __shfl_xor(q, 32);
    if (lane < 16) {
      atomicAdd(&stats[col], s);
      atomicAdd(&stats[DD + col], q);
    }
  }
}

// ---------------------------------------------------------------- BN finalize
__global__ void bn_finalize_k(const float* __restrict__ stats,
                              const float* __restrict__ gamma,
                              const float* __restrict__ beta,
                              float* __restrict__ scsh) {
  int j = threadIdx.x;  // 128
  float mean = stats[j] * (1.f / NN);
  float var = stats[DD + j] * (1.f / NN) - mean * mean;
  float inv = rsqrtf(var + BN_EPS);
  float sc = gamma[j] * inv;
  scsh[j] = sc;
  scsh[DD + j] = beta[j] - mean * sc;
}

// ---------------------------------------------------------------- normalize+ReLU
__global__ __launch_bounds__(256) void bn_relu_k(float* __restrict__ out,
                                                 const float* __restrict__ scsh) {
  long long i4 = (long long)blockIdx.x * 256 + threadIdx.x;  // 3.2M float4 exact
  int c4 = (int)(i4 & 31);
  f32x4 sc = *(const f32x4*)(scsh + c4 * 4);
  f32x4 sh = *(const f32x4*)(scsh + DD + c4 * 4);
  f32x4 v = *((f32x4*)out + i4);
#pragma unroll
  for (int k = 0; k < 4; ++k) v[k] = fmaxf(v[k] * sc[k] + sh[k], 0.f);
  *((f32x4*)out + i4) = v;
}

// ---------------------------------------------------------------- launch
extern "C" void kernel_launch(void* const* d_in, const int* in_sizes, int n_in,
                              void* d_out, int out_size, void* d_ws, size_t ws_size,
                              hipStream_t stream) {
  const float* x     = (const float*)d_in[0];
  const int*   lei   = (const int*)d_in[1];
  const int*   gei   = (const int*)d_in[2];
  const float* W1    = (const float*)d_in[3];
  const float* W2L   = (const float*)d_in[4];
  const float* W2G   = (const float*)d_in[5];
  const float* gamma = (const float*)d_in[6];
  const float* beta  = (const float*)d_in[7];
  float* out = (float*)d_out;

  const size_t AGG_BYTES = (size_t)NN * DD * 4;          // 51.2 MB
  float* aggL = (float*)d_ws;
  unsigned short* Bw = (unsigned short*)((char*)d_ws + AGG_BYTES);
  float* stats = (float*)((char*)d_ws + AGG_BYTES + (size_t)DD * KT * 2);
  float* scsh = stats + 256;
  float* aggG = out;  // alias: safe (GEMM block reads only its own rows)

  size_t zero_bytes = AGG_BYTES + (size_t)DD * KT * 2 + 256 * 4;
  hipMemsetAsync(d_ws, 0, zero_bytes, stream);
  hipMemsetAsync(d_out, 0, AGG_BYTES, stream);

  packB_k<<<(DD * KT) / 256, 256, 0, stream>>>(W1, W2L, W2G, Bw);
  scatter_k<<<(2 * EE * 32) / 256, 256, 0, stream>>>(x, lei, gei, aggL, aggG);
  gemm_k<<<(NN + 127) / 128, 256, 0, stream>>>(x, aggL, aggG, Bw, out, stats);
  bn_finalize_k<<<1, 128, 0, stream>>>(stats, gamma, beta, scsh);
  bn_relu_k<<<(NN * DD / 4) / 256, 256, 0, stream>>>(out, scsh);
}

// Round 2
// 698.207 us; speedup vs baseline: 5.0456x; 5.0456x over previous
//
#include <hip/hip_runtime.h>
#include <hip/hip_bf16.h>
#include <cstdint>

#define NN 100000
#define DD 128
#define EE 1000000
#define KT 384
#define BN_EPS 1e-5f

typedef __attribute__((ext_vector_type(4))) float f32x4;
typedef __attribute__((ext_vector_type(8))) short bf16x8;
typedef __attribute__((ext_vector_type(4))) unsigned short u16x4;
typedef __attribute__((ext_vector_type(8))) unsigned short u16x8;

__device__ __forceinline__ unsigned short f2bf(float f) {
  union { float f; unsigned u; } c; c.f = f;
  unsigned u = c.u;
  return (unsigned short)((u + 0x7FFFu + ((u >> 16) & 1u)) >> 16);  // RNE
}

// ================================================================ CSR build
// combined row index space: set L rows = [0,NN), set G rows = [NN,2NN)
__global__ __launch_bounds__(256) void hist_k(const int* __restrict__ lei,
                                              const int* __restrict__ gei,
                                              int* __restrict__ cnt) {
  int t = blockIdx.x * 256 + threadIdx.x;
  if (t >= 2 * EE) return;
  int s = t >= EE;
  const int* ei = s ? gei : lei;
  int row = ei[t - s * EE];
  atomicAdd(&cnt[s * NN + row], 1);
}

// in-place exclusive scan, phase 1: per-block (1024 items) scan + block totals
__global__ __launch_bounds__(256) void scan1_k(int* __restrict__ off,
                                               int* __restrict__ partial, int n) {
  __shared__ int wsum[4];
  int t = threadIdx.x;
  int base = blockIdx.x * 1024 + t * 4;
  int v[4];
#pragma unroll
  for (int k = 0; k < 4; ++k) { int i = base + k; v[k] = (i < n) ? off[i] : 0; }
  int tot = v[0] + v[1] + v[2] + v[3];
  int lane = t & 63, wv = t >> 6;
  int inc = tot;
  for (int d = 1; d < 64; d <<= 1) { int u = __shfl_up(inc, d); if (lane >= d) inc += u; }
  if (lane == 63) wsum[wv] = inc;
  __syncthreads();
  int woff = 0;
#pragma unroll
  for (int w = 0; w < 4; ++w) if (w < wv) woff += wsum[w];
  int run = woff + inc - tot;  // block-exclusive prefix for this thread
#pragma unroll
  for (int k = 0; k < 4; ++k) { int i = base + k; if (i < n) off[i] = run; run += v[k]; }
  if (t == 0) partial[blockIdx.x] = wsum[0] + wsum[1] + wsum[2] + wsum[3];
}

// phase 2: serial exclusive scan of block totals (nb ~ 196)
__global__ void scan2_k(int* __restrict__ partial, int nb) {
  if (threadIdx.x == 0) {
    int s = 0;
    for (int i = 0; i < nb; ++i) { int v = partial[i]; partial[i] = s; s += v; }
  }
}

// phase 3: add block offsets; copy to cursor; write sentinel
__global__ __launch_bounds__(256) void scan3_k(int* __restrict__ off,
                                               int* __restrict__ cursor,
                                               const int* __restrict__ partial, int n) {
  int i = blockIdx.x * 256 + threadIdx.x;
  if (i < n) { int v = off[i] + partial[i >> 10]; off[i] = v; cursor[i] = v; }
  if (i == n) off[n] = 2 * EE;
}

__global__ __launch_bounds__(256) void build_k(const int* __restrict__ lei,
                                               const int* __restrict__ gei,
                                               int* __restrict__ cursor,
                                               int* __restrict__ colS) {
  int t = blockIdx.x * 256 + threadIdx.x;
  if (t >= 2 * EE) return;
  int s = t >= EE;
  const int* ei = s ? gei : lei;
  int e = t - s * EE;
  int row = ei[e], col = ei[EE + e];
  int pos = atomicAdd(&cursor[s * NN + row], 1);
  colS[pos] = col;
}

// gather: 32 lanes per row (float4/lane), f32 register accumulate, one write
__global__ __launch_bounds__(256) void gather_k(const float* __restrict__ x,
                                                const int* __restrict__ off,
                                                const int* __restrict__ colS,
                                                float* __restrict__ aggL,
                                                float* __restrict__ aggG) {
  int g = blockIdx.x * 8 + (threadIdx.x >> 5);
  if (g >= 2 * NN) return;
  int lane = threadIdx.x & 31;
  int s0 = off[g], s1 = off[g + 1];
  f32x4 acc = (f32x4){0.f, 0.f, 0.f, 0.f};
  for (int i = s0; i < s1; ++i) {
    int col = colS[i];
    f32x4 v = *(const f32x4*)(x + (size_t)col * DD + lane * 4);
    acc[0] += v[0]; acc[1] += v[1]; acc[2] += v[2]; acc[3] += v[3];
  }
  float* dst = (g < NN) ? (aggL + (size_t)g * DD) : (aggG + (size_t)(g - NN) * DD);
  *(f32x4*)(dst + lane * 4) = acc;
}

// ================================================================ fallback scatter
__global__ __launch_bounds__(256) void scatter_k(
    const float* __restrict__ x, const int* __restrict__ lei,
    const int* __restrict__ gei, float* __restrict__ aggL,
    float* __restrict__ aggG) {
  long long gt = (long long)blockIdx.x * 256 + threadIdx.x;
  long long eg = gt >> 5;
  int f = (int)(gt & 31);
  const int* ei; float* agg; int e;
  if (eg < EE) { ei = lei; agg = aggL; e = (int)eg; }
  else         { ei = gei; agg = aggG; e = (int)(eg - EE); }
  int row = ei[e];
  int col = ei[EE + e];
  f32x4 v = *(const f32x4*)(x + (size_t)col * DD + f * 4);
  float* dst = agg + (size_t)row * DD + f * 4;
  atomicAdd(dst + 0, v[0]);
  atomicAdd(dst + 1, v[1]);
  atomicAdd(dst + 2, v[2]);
  atomicAdd(dst + 3, v[3]);
}

// ================================================================ pack B
__global__ __launch_bounds__(256) void packB_k(
    const float* __restrict__ W1, const float* __restrict__ W2L,
    const float* __restrict__ W2G, unsigned short* __restrict__ Bw) {
  int t = blockIdx.x * 256 + threadIdx.x;  // < 128*384
  int j = t / KT, k = t - j * KT;
  const float* W = (k < DD) ? W1 : ((k < 2 * DD) ? W2L : W2G);
  Bw[t] = f2bf(W[j * DD + (k & (DD - 1))]);
}

// ================================================================ GEMM
// out[N,128] = [x | aggL | aggG] (K=384, bf16) @ B[384,128]
__global__ __launch_bounds__(256) void gemm_k(
    const float* __restrict__ x, const float* __restrict__ aggL,
    const float* __restrict__ aggG, const unsigned short* __restrict__ Bw,
    float* __restrict__ out, float* __restrict__ stats) {
  __shared__ unsigned short Asm[128 * 32];
  __shared__ unsigned short Bsm[128 * 32];
  int t = threadIdx.x;
  int wave = t >> 6, lane = t & 63;
  int row0 = blockIdx.x * 128;

  f32x4 acc[2][8];
#pragma unroll
  for (int mi = 0; mi < 2; ++mi)
#pragma unroll
    for (int ni = 0; ni < 8; ++ni) acc[mi][ni] = (f32x4){0.f, 0.f, 0.f, 0.f};

  for (int step = 0; step < 12; ++step) {
    const float* Asrc = (step < 4) ? x : ((step < 8) ? aggL : aggG);
    int c0 = (step & 3) * 32;
    int k0 = step * 32;
#pragma unroll
    for (int i = 0; i < 4; ++i) {
      int flat = t + i * 256;
      int r = flat >> 3, kq = flat & 7;
      f32x4 v = (f32x4){0.f, 0.f, 0.f, 0.f};
      if (row0 + r < NN)
        v = *(const f32x4*)(Asrc + (size_t)(row0 + r) * DD + c0 + kq * 4);
      u16x4 h;
      h[0] = f2bf(v[0]); h[1] = f2bf(v[1]); h[2] = f2bf(v[2]); h[3] = f2bf(v[3]);
      *(u16x4*)(&Asm[r * 32 + kq * 4]) = h;
    }
#pragma unroll
    for (int i = 0; i < 2; ++i) {
      int flat = t + i * 256;
      int r = flat >> 2, kq8 = flat & 3;
      u16x8 w = *(const u16x8*)(Bw + (size_t)r * KT + k0 + kq8 * 8);
      *(u16x8*)(&Bsm[r * 32 + kq8 * 8]) = w;
    }
    __syncthreads();
    int mrow = lane & 15, kg = (lane >> 4) * 8;
    bf16x8 a0 = *(const bf16x8*)(&Asm[(wave * 32 + mrow) * 32 + kg]);
    bf16x8 a1 = *(const bf16x8*)(&Asm[(wave * 32 + 16 + mrow) * 32 + kg]);
#pragma unroll
    for (int ni = 0; ni < 8; ++ni) {
      bf16x8 b = *(const bf16x8*)(&Bsm[(ni * 16 + mrow) * 32 + kg]);
      acc[0][ni] = __builtin_amdgcn_mfma_f32_16x16x32_bf16(a0, b, acc[0][ni], 0, 0, 0);
      acc[1][ni] = __builtin_amdgcn_mfma_f32_16x16x32_bf16(a1, b, acc[1][ni], 0, 0, 0);
    }
    __syncthreads();
  }

  int colbase = lane & 15;
  int rbase = (lane >> 4) * 4;
#pragma unroll
  for (int ni = 0; ni < 8; ++ni) {
    int col = ni * 16 + colbase;
    float s = 0.f, q = 0.f;
#pragma unroll
    for (int mi = 0; mi < 2; ++mi) {
#pragma unroll
      for (int r = 0; r < 4; ++r) {
        int row = row0 + wave * 32 + mi * 16 + rbase + r;
        float v = acc[mi][ni][r];
        if (row < NN) {
          out[(size_t)row * DD + col] = v;
          s += v; q += v * v;
        }
      }
    }
    s += __shfl_xor(s, 16); s += __shfl_xor(s, 32);
    q += __shfl_xor(q, 16); q += __shfl_xor(q, 32);
    if (lane < 16) {
      atomicAdd(&stats[col], s);
      atomicAdd(&stats[DD + col], q);
    }
  }
}

// ================================================================ BN finalize
__global__ void bn_finalize_k(const float* __restrict__ stats,
                              const float* __restrict__ gamma,
                              const float* __restrict__ beta,
                              float* __restrict__ scsh) {
  int j = threadIdx.x;
  float mean = stats[j] * (1.f / NN);
  float var = stats[DD + j] * (1.f / NN) - mean * mean;
  float inv = rsqrtf(var + BN_EPS);
  float sc = gamma[j] * inv;
  scsh[j] = sc;
  scsh[DD + j] = beta[j] - mean * sc;
}

// ================================================================ BN apply + ReLU
__global__ __launch_bounds__(256) void bn_relu_k(float* __restrict__ out,
                                                 const float* __restrict__ scsh) {
  long long i4 = (long long)blockIdx.x * 256 + threadIdx.x;
  int c4 = (int)(i4 & 31);
  f32x4 sc = *(const f32x4*)(scsh + c4 * 4);
  f32x4 sh = *(const f32x4*)(scsh + DD + c4 * 4);
  f32x4 v = *((f32x4*)out + i4);
#pragma unroll
  for (int k = 0; k < 4; ++k) v[k] = fmaxf(v[k] * sc[k] + sh[k], 0.f);
  *((f32x4*)out + i4) = v;
}

// ================================================================ launch
extern "C" void kernel_launch(void* const* d_in, const int* in_sizes, int n_in,
                              void* d_out, int out_size, void* d_ws, size_t ws_size,
                              hipStream_t stream) {
  const float* x     = (const float*)d_in[0];
  const int*   lei   = (const int*)d_in[1];
  const int*   gei   = (const int*)d_in[2];
  const float* W1    = (const float*)d_in[3];
  const float* W2L   = (const float*)d_in[4];
  const float* W2G   = (const float*)d_in[5];
  const float* gamma = (const float*)d_in[6];
  const float* beta  = (const float*)d_in[7];
  float* out = (float*)d_out;

  const size_t AGG_BYTES = (size_t)NN * DD * 4;  // 51.2 MB
  char* w = (char*)d_ws;

  // CSR layout
  size_t o = 0;
  float* aggL = (float*)(w + o); o += AGG_BYTES;                     // 51,200,000
  int* colS   = (int*)(w + o);   o += (size_t)2 * EE * 4;            // +8,000,000
  int* off    = (int*)(w + o);   size_t off_o = o; o += ((size_t)2 * NN + 1) * 4 + 12; // (cnt aliases off)
  int* cursor = (int*)(w + o);   o += (size_t)2 * NN * 4;
  int* partial= (int*)(w + o);   o += 1024;
  size_t zero_end = o;
  unsigned short* Bw = (unsigned short*)(w + o); o += (size_t)DD * KT * 2;
  float* stats = (float*)(w + o); o += 1024;
  float* scsh  = (float*)(w + o); o += 1024;
  size_t NEED = o;

  float* aggG = out;  // alias: GEMM block reads only its own rows

  if (ws_size >= NEED) {
    // ---- CSR path ----
    hipMemsetAsync(w + off_o, 0, zero_end - off_o, stream);  // cnt/cursor/partial
    hipMemsetAsync(stats, 0, 2048, stream);

    int nb2e = (2 * EE + 255) / 256;
    hist_k<<<nb2e, 256, 0, stream>>>(lei, gei, off);
    int nscan = 2 * NN;
    int nb1 = (nscan + 1023) / 1024;
    scan1_k<<<nb1, 256, 0, stream>>>(off, partial, nscan);
    scan2_k<<<1, 64, 0, stream>>>(partial, nb1);
    scan3_k<<<(nscan + 256) / 256, 256, 0, stream>>>(off, cursor, partial, nscan);
    build_k<<<nb2e, 256, 0, stream>>>(lei, gei, cursor, colS);
    gather_k<<<(2 * NN + 7) / 8, 256, 0, stream>>>(x, off, colS, aggL, aggG);
  } else {
    // ---- fallback: atomic scatter (round-1 path) ----
    unsigned short* BwF = (unsigned short*)(w + AGG_BYTES);
    float* statsF = (float*)(w + AGG_BYTES + (size_t)DD * KT * 2);
    float* scshF = statsF + 256;
    Bw = BwF; stats = statsF; scsh = scshF;
    hipMemsetAsync(d_ws, 0, AGG_BYTES + (size_t)DD * KT * 2 + 2048, stream);
    hipMemsetAsync(d_out, 0, AGG_BYTES, stream);
    scatter_k<<<(2 * EE * 32) / 256, 256, 0, stream>>>(x, lei, gei, aggL, aggG);
  }

  packB_k<<<(DD * KT) / 256, 256, 0, stream>>>(W1, W2L, W2G, Bw);
  gemm_k<<<(NN + 127) / 128, 256, 0, stream>>>(x, aggL, aggG, Bw, out, stats);
  bn_finalize_k<<<1, 128, 0, stream>>>(stats, gamma, beta, scsh);
  bn_relu_k<<<(NN * DD / 4) / 256, 256, 0, stream>>>(out, scsh);
}

// Round 3
// 434.283 us; speedup vs baseline: 8.1120x; 1.6077x over previous
//
#include <hip/hip_runtime.h>
#include <cstdint>

#define NN 100000
#define DD 128
#define EE 1000000
#define BN_EPS 1e-5f

typedef __attribute__((ext_vector_type(4))) float f32x4;
typedef __attribute__((ext_vector_type(8))) short bf16x8;
typedef __attribute__((ext_vector_type(8))) unsigned short u16x8;

__device__ __forceinline__ unsigned short f2bf(float f) {
  union { float f; unsigned u; } c; c.f = f;
  unsigned u = c.u;
  return (unsigned short)((u + 0x7FFFu + ((u >> 16) & 1u)) >> 16);  // RNE
}
__device__ __forceinline__ float bf2f(unsigned short h) {
  union { unsigned u; float f; } c; c.u = ((unsigned)h) << 16;
  return c.f;
}
__device__ __forceinline__ void gld16(const void* g, void* l) {
  __builtin_amdgcn_global_load_lds(
      (const __attribute__((address_space(1))) unsigned int*)g,
      (__attribute__((address_space(3))) unsigned int*)l, 16, 0, 0);
}

// ---------------------------------------------------------------- x -> bf16 (strided into d_out: row r at byte r*512)
__global__ __launch_bounds__(256) void xcvt_k(const float* __restrict__ x,
                                              char* __restrict__ xb) {
  int i8 = blockIdx.x * 256 + threadIdx.x;  // 1.6M exact
  int row = i8 >> 4, c = i8 & 15;
  const float* src = x + (size_t)row * DD + c * 8;
  f32x4 v0 = *(const f32x4*)src;
  f32x4 v1 = *(const f32x4*)(src + 4);
  u16x8 h;
  h[0] = f2bf(v0[0]); h[1] = f2bf(v0[1]); h[2] = f2bf(v0[2]); h[3] = f2bf(v0[3]);
  h[4] = f2bf(v1[0]); h[5] = f2bf(v1[1]); h[6] = f2bf(v1[2]); h[7] = f2bf(v1[3]);
  *(u16x8*)(xb + (size_t)row * 512 + c * 16) = h;
}

// ---------------------------------------------------------------- CSR build
__global__ __launch_bounds__(256) void hist_k(const int* __restrict__ lei,
                                              const int* __restrict__ gei,
                                              int* __restrict__ cnt) {
  int t = blockIdx.x * 256 + threadIdx.x;
  if (t >= 2 * EE) return;
  int s = t >= EE;
  const int* ei = s ? gei : lei;
  int row = ei[t - s * EE];
  atomicAdd(&cnt[s * NN + row], 1);
}

__global__ __launch_bounds__(256) void scan1_k(int* __restrict__ off,
                                               int* __restrict__ partial, int n) {
  __shared__ int wsum[4];
  int t = threadIdx.x;
  int base = blockIdx.x * 1024 + t * 4;
  int v[4];
#pragma unroll
  for (int k = 0; k < 4; ++k) { int i = base + k; v[k] = (i < n) ? off[i] : 0; }
  int tot = v[0] + v[1] + v[2] + v[3];
  int lane = t & 63, wv = t >> 6;
  int inc = tot;
  for (int d = 1; d < 64; d <<= 1) { int u = __shfl_up(inc, d); if (lane >= d) inc += u; }
  if (lane == 63) wsum[wv] = inc;
  __syncthreads();
  int woff = 0;
#pragma unroll
  for (int w = 0; w < 4; ++w) if (w < wv) woff += wsum[w];
  int run = woff + inc - tot;
#pragma unroll
  for (int k = 0; k < 4; ++k) { int i = base + k; if (i < n) off[i] = run; run += v[k]; }
  if (t == 0) partial[blockIdx.x] = wsum[0] + wsum[1] + wsum[2] + wsum[3];
}

__global__ void scan2_k(int* __restrict__ partial, int nb) {
  if (threadIdx.x == 0) {
    int s = 0;
    for (int i = 0; i < nb; ++i) { int v = partial[i]; partial[i] = s; s += v; }
  }
}

__global__ __launch_bounds__(256) void scan3_k(int* __restrict__ off,
                                               int* __restrict__ cursor,
                                               const int* __restrict__ partial, int n) {
  int i = blockIdx.x * 256 + threadIdx.x;
  if (i < n) { int v = off[i] + partial[i >> 10]; off[i] = v; cursor[i] = v; }
  if (i == n) off[n] = 2 * EE;
}

__global__ __launch_bounds__(256) void build_k(const int* __restrict__ lei,
                                               const int* __restrict__ gei,
                                               int* __restrict__ cursor,
                                               int* __restrict__ colS) {
  int t = blockIdx.x * 256 + threadIdx.x;
  if (t >= 2 * EE) return;
  int s = t >= EE;
  const int* ei = s ? gei : lei;
  int e = t - s * EE;
  int row = ei[e], col = ei[EE + e];
  int pos = atomicAdd(&cursor[s * NN + row], 1);
  colS[pos] = col;
}

// ---------------------------------------------------------------- gather (bf16 in, bf16 out)
__global__ __launch_bounds__(256) void gather_k(const char* __restrict__ xb,
                                                const int* __restrict__ off,
                                                const int* __restrict__ colS,
                                                unsigned short* __restrict__ aggLb,
                                                unsigned short* __restrict__ aggGb) {
  int g = blockIdx.x * 16 + (threadIdx.x >> 4);
  if (g >= 2 * NN) return;
  int lane = threadIdx.x & 15;
  int s0 = off[g], s1 = off[g + 1];
  float a[8] = {0.f, 0.f, 0.f, 0.f, 0.f, 0.f, 0.f, 0.f};
  for (int i = s0; i < s1; ++i) {
    int col = colS[i];
    u16x8 v = *(const u16x8*)(xb + (size_t)col * 512 + lane * 16);
#pragma unroll
    for (int j = 0; j < 8; ++j) a[j] += bf2f(v[j]);
  }
  u16x8 h;
#pragma unroll
  for (int j = 0; j < 8; ++j) h[j] = f2bf(a[j]);
  unsigned short* dst = (g < NN) ? (aggLb + (size_t)g * DD)
                                 : (aggGb + (size_t)(g - NN) * DD);
  *(u16x8*)(dst + lane * 8) = h;
}

// ---------------------------------------------------------------- pack B [128][384] bf16
__global__ __launch_bounds__(256) void packB_k(
    const float* __restrict__ W1, const float* __restrict__ W2L,
    const float* __restrict__ W2G, unsigned short* __restrict__ Bw) {
  int t = blockIdx.x * 256 + threadIdx.x;  // < 128*384
  int j = t / 384, k = t - j * 384;
  const float* W = (k < DD) ? W1 : ((k < 2 * DD) ? W2L : W2G);
  Bw[t] = f2bf(W[j * DD + (k & (DD - 1))]);
}

// ---------------------------------------------------------------- GEMM (bf16 A via global_load_lds, dbuf, swizzled)
__global__ __launch_bounds__(256, 2) void gemm_k(
    const char* __restrict__ xb, const unsigned short* __restrict__ aggLb,
    const unsigned short* __restrict__ aggGb, const unsigned short* __restrict__ Bw,
    float* __restrict__ out, float* __restrict__ stats) {
  __shared__ unsigned short Asm[2][128 * 64];  // 16KB each, linear chunks
  __shared__ unsigned short Bsm[2][128 * 64];
  __shared__ float red[4][256];
  int t = threadIdx.x, wave = t >> 6, lane = t & 63;
  int row0 = blockIdx.x * 128;

  f32x4 acc[2][8];
#pragma unroll
  for (int mi = 0; mi < 2; ++mi)
#pragma unroll
    for (int ni = 0; ni < 8; ++ni) acc[mi][ni] = (f32x4){0.f, 0.f, 0.f, 0.f};

  // stage K-window s (64 cols) into buffer b. LDS dest linear; global source
  // pre-swizzled (chunk c_l holds global chunk c_l ^ (row&7)) [m173 pattern]
  auto STAGE = [&](int s, int b) {
#pragma unroll
    for (int i = 0; i < 4; ++i) {
      int flat = t + i * 256, r = flat >> 3, c = flat & 7;
      int rr = row0 + r; rr = (rr < NN) ? rr : (NN - 1);  // clamp stays in-block
      const char* src;
      if (s < 2)      src = xb + (size_t)rr * 512 + (s & 1) * 128 + ((c ^ (r & 7)) << 4);
      else if (s < 4) src = (const char*)aggLb + (size_t)rr * 256 + (s & 1) * 128 + ((c ^ (r & 7)) << 4);
      else            src = (const char*)aggGb + (size_t)rr * 256 + (s & 1) * 128 + ((c ^ (r & 7)) << 4);
      gld16(src, &Asm[b][(size_t)(i * 256 + wave * 64) * 8]);
    }
#pragma unroll
    for (int i = 0; i < 4; ++i) {
      int flat = t + i * 256, n = flat >> 3, c = flat & 7;
      const char* src = (const char*)Bw + (size_t)n * 768 + s * 128 + ((c ^ (n & 7)) << 4);
      gld16(src, &Bsm[b][(size_t)(i * 256 + wave * 64) * 8]);
    }
  };

  auto COMPUTE = [&](int b) {
    int mr = lane & 15, kq = lane >> 4;
#pragma unroll
    for (int ki = 0; ki < 2; ++ki) {
      int kg = ki * 4 + kq;
      int r0 = wave * 32 + mr, r1 = r0 + 16;
      bf16x8 a0 = *(const bf16x8*)&Asm[b][((size_t)r0 * 8 + (kg ^ (r0 & 7))) * 8];
      bf16x8 a1 = *(const bf16x8*)&Asm[b][((size_t)r1 * 8 + (kg ^ (r1 & 7))) * 8];
#pragma unroll
      for (int ni = 0; ni < 8; ++ni) {
        int nr = ni * 16 + mr;
        bf16x8 bb = *(const bf16x8*)&Bsm[b][((size_t)nr * 8 + (kg ^ (nr & 7))) * 8];
        acc[0][ni] = __builtin_amdgcn_mfma_f32_16x16x32_bf16(a0, bb, acc[0][ni], 0, 0, 0);
        acc[1][ni] = __builtin_amdgcn_mfma_f32_16x16x32_bf16(a1, bb, acc[1][ni], 0, 0, 0);
      }
    }
  };

  STAGE(0, 0);
  __syncthreads();
#pragma unroll
  for (int s = 0; s < 6; ++s) {
    int b = s & 1;
    if (s < 5) STAGE(s + 1, b ^ 1);   // prefetch next window
    COMPUTE(b);
    __syncthreads();                   // drains vmcnt(0): prefetch landed
  }

  // epilogue: C/D layout col=lane&15, row=(lane>>4)*4+reg
  int colbase = lane & 15, rbase = (lane >> 4) * 4;
#pragma unroll
  for (int ni = 0; ni < 8; ++ni) {
    int col = ni * 16 + colbase;
    float s = 0.f, q = 0.f;
#pragma unroll
    for (int mi = 0; mi < 2; ++mi)
#pragma unroll
      for (int r = 0; r < 4; ++r) {
        int row = row0 + wave * 32 + mi * 16 + rbase + r;
        float v = acc[mi][ni][r];
        if (row < NN) {
          out[(size_t)row * DD + col] = v;
          s += v; q += v * v;
        }
      }
    s += __shfl_xor(s, 16); s += __shfl_xor(s, 32);
    q += __shfl_xor(q, 16); q += __shfl_xor(q, 32);
    if (lane < 16) { red[wave][col] = s; red[wave][128 + col] = q; }
  }
  __syncthreads();
  float v = red[0][t & 255] + red[1][t & 255] + red[2][t & 255] + red[3][t & 255];
  atomicAdd(&stats[t & 255], v);
}

// ---------------------------------------------------------------- BN finalize
__global__ void bn_finalize_k(const float* __restrict__ stats,
                              const float* __restrict__ gamma,
                              const float* __restrict__ beta,
                              float* __restrict__ scsh) {
  int j = threadIdx.x;
  float mean = stats[j] * (1.f / NN);
  float var = stats[DD + j] * (1.f / NN) - mean * mean;
  float inv = rsqrtf(var + BN_EPS);
  float sc = gamma[j] * inv;
  scsh[j] = sc;
  scsh[DD + j] = beta[j] - mean * sc;
}

// ---------------------------------------------------------------- BN apply + ReLU
__global__ __launch_bounds__(256) void bn_relu_k(float* __restrict__ out,
                                                 const float* __restrict__ scsh) {
  long long i4 = (long long)blockIdx.x * 256 + threadIdx.x;  // 3.2M exact
  int c4 = (int)(i4 & 31);
  f32x4 sc = *(const f32x4*)(scsh + c4 * 4);
  f32x4 sh = *(const f32x4*)(scsh + DD + c4 * 4);
  f32x4 v = *((f32x4*)out + i4);
#pragma unroll
  for (int k = 0; k < 4; ++k) v[k] = fmaxf(v[k] * sc[k] + sh[k], 0.f);
  *((f32x4*)out + i4) = v;
}

// ---------------------------------------------------------------- launch
extern "C" void kernel_launch(void* const* d_in, const int* in_sizes, int n_in,
                              void* d_out, int out_size, void* d_ws, size_t ws_size,
                              hipStream_t stream) {
  const float* x     = (const float*)d_in[0];
  const int*   lei   = (const int*)d_in[1];
  const int*   gei   = (const int*)d_in[2];
  const float* W1    = (const float*)d_in[3];
  const float* W2L   = (const float*)d_in[4];
  const float* W2G   = (const float*)d_in[5];
  const float* gamma = (const float*)d_in[6];
  const float* beta  = (const float*)d_in[7];
  float* out = (float*)d_out;
  char* xb = (char*)d_out;  // bf16 x, row r at byte r*512 (first 256B of out row r)

  char* w = (char*)d_ws;
  size_t o = 0;
  unsigned short* aggLb = (unsigned short*)(w + o); o += (size_t)NN * DD * 2;   // 25.6MB
  unsigned short* aggGb = (unsigned short*)(w + o); o += (size_t)NN * DD * 2;   // 25.6MB
  int* colS   = (int*)(w + o); o += (size_t)2 * EE * 4;                          // 8MB
  int* off    = (int*)(w + o); size_t zs = o; o += ((size_t)2 * NN + 1) * 4 + 28; // pad->16
  int* cursor = (int*)(w + o); o += (size_t)2 * NN * 4;
  int* partial= (int*)(w + o); o += 1024;
  size_t ze = o;
  unsigned short* Bw = (unsigned short*)(w + o); o += (size_t)DD * 384 * 2;      // 96KB
  float* stats = (float*)(w + o); o += 1024;
  float* scsh  = (float*)(w + o); o += 1024;

  hipMemsetAsync(w + zs, 0, ze - zs, stream);   // cnt/cursor/partial
  hipMemsetAsync(stats, 0, 1024, stream);

  xcvt_k<<<(NN * DD / 8) / 256, 256, 0, stream>>>(x, xb);
  packB_k<<<(DD * 384) / 256, 256, 0, stream>>>(W1, W2L, W2G, Bw);

  int nb2e = (2 * EE + 255) / 256;
  hist_k<<<nb2e, 256, 0, stream>>>(lei, gei, off);
  int nscan = 2 * NN;
  int nb1 = (nscan + 1023) / 1024;
  scan1_k<<<nb1, 256, 0, stream>>>(off, partial, nscan);
  scan2_k<<<1, 64, 0, stream>>>(partial, nb1);
  scan3_k<<<(nscan + 256) / 256, 256, 0, stream>>>(off, cursor, partial, nscan);
  build_k<<<nb2e, 256, 0, stream>>>(lei, gei, cursor, colS);
  gather_k<<<(2 * NN + 15) / 16, 256, 0, stream>>>(xb, off, colS, aggLb, aggGb);

  gemm_k<<<(NN + 127) / 128, 256, 0, stream>>>(xb, aggLb, aggGb, Bw, out, stats);
  bn_finalize_k<<<1, 128, 0, stream>>>(stats, gamma, beta, scsh);
  bn_relu_k<<<(NN * DD / 4) / 256, 256, 0, stream>>>(out, scsh);
}

// Round 4
// 255.082 us; speedup vs baseline: 13.8109x; 1.7025x over previous
//
#include <hip/hip_runtime.h>
#include <cstdint>

#define NN 100000
#define DD 128
#define EE 1000000
#define NB 782          // ceil(2*NN/256) buckets of 256 rows
#define CHUNK 8192      // edges per multisplit block
#define CAP 8192        // max edges per bucket (mean 2560, sigma ~51)
#define BN_EPS 1e-5f

typedef __attribute__((ext_vector_type(4))) float f32x4;
typedef __attribute__((ext_vector_type(8))) short bf16x8;
typedef __attribute__((ext_vector_type(8))) unsigned short u16x8;

__device__ __forceinline__ unsigned short f2bf(float f) {
  union { float f; unsigned u; } c; c.f = f;
  unsigned u = c.u;
  return (unsigned short)((u + 0x7FFFu + ((u >> 16) & 1u)) >> 16);  // RNE
}
__device__ __forceinline__ float bf2f(unsigned short h) {
  union { unsigned u; float f; } c; c.u = ((unsigned)h) << 16;
  return c.f;
}
__device__ __forceinline__ void gld16(const void* g, void* l) {
  __builtin_amdgcn_global_load_lds(
      (const __attribute__((address_space(1))) unsigned int*)g,
      (__attribute__((address_space(3))) unsigned int*)l, 16, 0, 0);
}

// ---------------------------------------------------------------- x -> bf16 (strided into d_out: row r at byte r*512)
__global__ __launch_bounds__(256) void xcvt_k(const float* __restrict__ x,
                                              char* __restrict__ xb) {
  int i8 = blockIdx.x * 256 + threadIdx.x;  // 1.6M exact
  int row = i8 >> 4, c = i8 & 15;
  const float* src = x + (size_t)row * DD + c * 8;
  f32x4 v0 = *(const f32x4*)src;
  f32x4 v1 = *(const f32x4*)(src + 4);
  u16x8 h;
  h[0] = f2bf(v0[0]); h[1] = f2bf(v0[1]); h[2] = f2bf(v0[2]); h[3] = f2bf(v0[3]);
  h[4] = f2bf(v1[0]); h[5] = f2bf(v1[1]); h[6] = f2bf(v1[2]); h[7] = f2bf(v1[3]);
  *(u16x8*)(xb + (size_t)row * 512 + c * 16) = h;
}

// ---------------------------------------------------------------- pack B [128][384] bf16
__global__ __launch_bounds__(256) void packB_k(
    const float* __restrict__ W1, const float* __restrict__ W2L,
    const float* __restrict__ W2G, unsigned short* __restrict__ Bw) {
  int t = blockIdx.x * 256 + threadIdx.x;
  int j = t / 384, k = t - j * 384;
  const float* W = (k < DD) ? W1 : ((k < 2 * DD) ? W2L : W2G);
  Bw[t] = f2bf(W[j * DD + (k & (DD - 1))]);
}

// ---------------------------------------------------------------- A1: bucket histogram (LDS-reduced)
__global__ __launch_bounds__(256) void bhist_k(const int* __restrict__ lei,
                                               const int* __restrict__ gei,
                                               int* __restrict__ gCnt) {
  __shared__ int hist[1024];
  int t = threadIdx.x;
#pragma unroll
  for (int k = 0; k < 4; ++k) hist[t * 4 + k] = 0;
  __syncthreads();
  int base = blockIdx.x * CHUNK;
#pragma unroll 4
  for (int j = 0; j < CHUNK / 256; ++j) {
    int i = base + j * 256 + t;
    if (i < 2 * EE) {
      int grow = (i < EE) ? lei[i] : (NN + gei[i - EE]);
      atomicAdd(&hist[grow >> 8], 1);
    }
  }
  __syncthreads();
#pragma unroll
  for (int k = 0; k < 4; ++k) {
    int b = t * 4 + k, c = hist[b];
    if (c) atomicAdd(&gCnt[b], c);
  }
}

// ---------------------------------------------------------------- A2: scan bucket counts (1 block)
__global__ __launch_bounds__(256) void bscan_k(const int* __restrict__ gCnt,
                                               int* __restrict__ gOff,
                                               int* __restrict__ gCur) {
  __shared__ int wsum[4];
  int t = threadIdx.x;
  int v[4];
#pragma unroll
  for (int k = 0; k < 4; ++k) v[k] = gCnt[t * 4 + k];
  int tot = v[0] + v[1] + v[2] + v[3];
  int lane = t & 63, wv = t >> 6;
  int inc = tot;
  for (int d = 1; d < 64; d <<= 1) { int u = __shfl_up(inc, d); if (lane >= d) inc += u; }
  if (lane == 63) wsum[wv] = inc;
  __syncthreads();
  int woff = 0;
#pragma unroll
  for (int w = 0; w < 4; ++w) if (w < wv) woff += wsum[w];
  int run = woff + inc - tot;
#pragma unroll
  for (int k = 0; k < 4; ++k) {
    gOff[t * 4 + k] = run; gCur[t * 4 + k] = run; run += v[k];
  }
  if (t == 255) gOff[1024] = run;  // = 2*EE
}

// ---------------------------------------------------------------- A3: multisplit scatter (LDS write-combining)
__global__ __launch_bounds__(256) void bscat_k(const int* __restrict__ lei,
                                               const int* __restrict__ gei,
                                               int* __restrict__ gCur,
                                               unsigned* __restrict__ edata) {
  __shared__ int lofs[1025];
  __shared__ int lcur[1024];
  __shared__ int gbase[1024];
  __shared__ unsigned short bid[CHUNK];
  __shared__ unsigned stage[CHUNK];
  __shared__ int wsum[4];
  int t = threadIdx.x;
  int base = blockIdx.x * CHUNK;
  int cnt = 2 * EE - base; if (cnt > CHUNK) cnt = CHUNK;
#pragma unroll
  for (int k = 0; k < 4; ++k) lofs[t * 4 + k] = 0;
  __syncthreads();
  // local bucket histogram
#pragma unroll 4
  for (int j = 0; j < CHUNK / 256; ++j) {
    int i = base + j * 256 + t;
    if (i < 2 * EE) {
      int grow = (i < EE) ? lei[i] : (NN + gei[i - EE]);
      atomicAdd(&lofs[grow >> 8], 1);
    }
  }
  __syncthreads();
  // local exclusive scan (thread owns 4 consecutive buckets)
  int v[4];
#pragma unroll
  for (int k = 0; k < 4; ++k) v[k] = lofs[t * 4 + k];
  int tot = v[0] + v[1] + v[2] + v[3];
  int lane = t & 63, wv = t >> 6;
  int inc = tot;
  for (int d = 1; d < 64; d <<= 1) { int u = __shfl_up(inc, d); if (lane >= d) inc += u; }
  if (lane == 63) wsum[wv] = inc;
  __syncthreads();
  int woff = 0;
#pragma unroll
  for (int w = 0; w < 4; ++w) if (w < wv) woff += wsum[w];
  int run = woff + inc - tot;
#pragma unroll
  for (int k = 0; k < 4; ++k) { lofs[t * 4 + k] = run; lcur[t * 4 + k] = run; run += v[k]; }
  if (t == 0) lofs[1024] = cnt;
  __syncthreads();
  // scatter into LDS staging (bucket-grouped)
#pragma unroll 4
  for (int j = 0; j < CHUNK / 256; ++j) {
    int i = base + j * 256 + t;
    if (i < 2 * EE) {
      int grow, col;
      if (i < EE) { grow = lei[i]; col = lei[EE + i]; }
      else        { grow = NN + gei[i - EE]; col = gei[i]; }
      int b = grow >> 8;
      int pos = atomicAdd(&lcur[b], 1);
      stage[pos] = (unsigned)col | ((unsigned)(grow & 255) << 24);
      bid[pos] = (unsigned short)b;
    }
  }
  __syncthreads();
  // reserve global space per bucket
#pragma unroll
  for (int k = 0; k < 4; ++k) {
    int b = t * 4 + k;
    int c = lofs[b + 1] - lofs[b];
    if (c > 0) gbase[b] = atomicAdd(&gCur[b], c);
  }
  __syncthreads();
  // coalesced-ish flush of bucket runs
  for (int i = t; i < cnt; i += 256) {
    int b = bid[i];
    edata[gbase[b] + (i - lofs[b])] = stage[i];
  }
}

// ---------------------------------------------------------------- B: per-bucket LDS CSR + gather
__global__ __launch_bounds__(256) void bgather_k(const char* __restrict__ xb,
                                                 const int* __restrict__ gOff,
                                                 const unsigned* __restrict__ edata,
                                                 unsigned short* __restrict__ aggLb,
                                                 unsigned short* __restrict__ aggGb) {
  __shared__ int rowOff[257];
  __shared__ int rowCur[256];
  __shared__ unsigned colS[CAP];
  __shared__ int wsum[4];
  int t = threadIdx.x;
  int b = blockIdx.x;
  int s0 = gOff[b];
  int cnt = gOff[b + 1] - s0; if (cnt > CAP) cnt = CAP;
  rowCur[t] = 0;
  __syncthreads();
  for (int i = t; i < cnt; i += 256)
    atomicAdd(&rowCur[edata[s0 + i] >> 24], 1);
  __syncthreads();
  // 256-entry exclusive scan
  int v = rowCur[t];
  int lane = t & 63, wv = t >> 6;
  int inc = v;
  for (int d = 1; d < 64; d <<= 1) { int u = __shfl_up(inc, d); if (lane >= d) inc += u; }
  if (lane == 63) wsum[wv] = inc;
  __syncthreads();
  int woff = 0;
#pragma unroll
  for (int w = 0; w < 4; ++w) if (w < wv) woff += wsum[w];
  int excl = woff + inc - v;
  rowOff[t] = excl;
  if (t == 255) rowOff[256] = excl + v;
  __syncthreads();
  rowCur[t] = excl;
  __syncthreads();
  // scatter cols into row-grouped LDS
  for (int i = t; i < cnt; i += 256) {
    unsigned e = edata[s0 + i];
    int pos = atomicAdd(&rowCur[e >> 24], 1);
    colS[pos] = e & 0xFFFFFFu;
  }
  __syncthreads();
  // gather: 16 lanes per row, 16 rows concurrent
  int lr0 = t >> 4, lane16 = t & 15;
  for (int r = lr0; r < 256; r += 16) {
    int grow = b * 256 + r;
    if (grow >= 2 * NN) break;
    int e0 = rowOff[r], e1 = rowOff[r + 1];
    float a[8] = {0.f, 0.f, 0.f, 0.f, 0.f, 0.f, 0.f, 0.f};
    for (int i = e0; i < e1; ++i) {
      unsigned col = colS[i];
      u16x8 x8 = *(const u16x8*)(xb + (size_t)col * 512 + lane16 * 16);
#pragma unroll
      for (int j = 0; j < 8; ++j) a[j] += bf2f(x8[j]);
    }
    u16x8 h;
#pragma unroll
    for (int j = 0; j < 8; ++j) h[j] = f2bf(a[j]);
    unsigned short* dst = (grow < NN) ? (aggLb + (size_t)grow * DD)
                                      : (aggGb + (size_t)(grow - NN) * DD);
    *(u16x8*)(dst + lane16 * 8) = h;
  }
}

// ---------------------------------------------------------------- GEMM (bf16 A via global_load_lds, dbuf, swizzled)
__global__ __launch_bounds__(256, 2) void gemm_k(
    const char* __restrict__ xb, const unsigned short* __restrict__ aggLb,
    const unsigned short* __restrict__ aggGb, const unsigned short* __restrict__ Bw,
    float* __restrict__ out, float* __restrict__ stats) {
  __shared__ unsigned short Asm[2][128 * 64];
  __shared__ unsigned short Bsm[2][128 * 64];
  __shared__ float red[4][256];
  int t = threadIdx.x, wave = t >> 6, lane = t & 63;
  int row0 = blockIdx.x * 128;

  f32x4 acc[2][8];
#pragma unroll
  for (int mi = 0; mi < 2; ++mi)
#pragma unroll
    for (int ni = 0; ni < 8; ++ni) acc[mi][ni] = (f32x4){0.f, 0.f, 0.f, 0.f};

  auto STAGE = [&](int s, int b) {
#pragma unroll
    for (int i = 0; i < 4; ++i) {
      int flat = t + i * 256, r = flat >> 3, c = flat & 7;
      int rr = row0 + r; rr = (rr < NN) ? rr : (NN - 1);
      const char* src;
      if (s < 2)      src = xb + (size_t)rr * 512 + (s & 1) * 128 + ((c ^ (r & 7)) << 4);
      else if (s < 4) src = (const char*)aggLb + (size_t)rr * 256 + (s & 1) * 128 + ((c ^ (r & 7)) << 4);
      else            src = (const char*)aggGb + (size_t)rr * 256 + (s & 1) * 128 + ((c ^ (r & 7)) << 4);
      gld16(src, &Asm[b][(size_t)(i * 256 + wave * 64) * 8]);
    }
#pragma unroll
    for (int i = 0; i < 4; ++i) {
      int flat = t + i * 256, n = flat >> 3, c = flat & 7;
      const char* src = (const char*)Bw + (size_t)n * 768 + s * 128 + ((c ^ (n & 7)) << 4);
      gld16(src, &Bsm[b][(size_t)(i * 256 + wave * 64) * 8]);
    }
  };

  auto COMPUTE = [&](int b) {
    int mr = lane & 15, kq = lane >> 4;
#pragma unroll
    for (int ki = 0; ki < 2; ++ki) {
      int kg = ki * 4 + kq;
      int r0 = wave * 32 + mr, r1 = r0 + 16;
      bf16x8 a0 = *(const bf16x8*)&Asm[b][((size_t)r0 * 8 + (kg ^ (r0 & 7))) * 8];
      bf16x8 a1 = *(const bf16x8*)&Asm[b][((size_t)r1 * 8 + (kg ^ (r1 & 7))) * 8];
#pragma unroll
      for (int ni = 0; ni < 8; ++ni) {
        int nr = ni * 16 + mr;
        bf16x8 bb = *(const bf16x8*)&Bsm[b][((size_t)nr * 8 + (kg ^ (nr & 7))) * 8];
        acc[0][ni] = __builtin_amdgcn_mfma_f32_16x16x32_bf16(a0, bb, acc[0][ni], 0, 0, 0);
        acc[1][ni] = __builtin_amdgcn_mfma_f32_16x16x32_bf16(a1, bb, acc[1][ni], 0, 0, 0);
      }
    }
  };

  STAGE(0, 0);
  __syncthreads();
#pragma unroll
  for (int s = 0; s < 6; ++s) {
    int b = s & 1;
    if (s < 5) STAGE(s + 1, b ^ 1);
    COMPUTE(b);
    __syncthreads();
  }

  int colbase = lane & 15, rbase = (lane >> 4) * 4;
#pragma unroll
  for (int ni = 0; ni < 8; ++ni) {
    int col = ni * 16 + colbase;
    float s = 0.f, q = 0.f;
#pragma unroll
    for (int mi = 0; mi < 2; ++mi)
#pragma unroll
      for (int r = 0; r < 4; ++r) {
        int row = row0 + wave * 32 + mi * 16 + rbase + r;
        float v = acc[mi][ni][r];
        if (row < NN) {
          out[(size_t)row * DD + col] = v;
          s += v; q += v * v;
        }
      }
    s += __shfl_xor(s, 16); s += __shfl_xor(s, 32);
    q += __shfl_xor(q, 16); q += __shfl_xor(q, 32);
    if (lane < 16) { red[wave][col] = s; red[wave][128 + col] = q; }
  }
  __syncthreads();
  float v = red[0][t & 255] + red[1][t & 255] + red[2][t & 255] + red[3][t & 255];
  atomicAdd(&stats[t & 255], v);
}

// ---------------------------------------------------------------- BN finalize
__global__ void bn_finalize_k(const float* __restrict__ stats,
                              const float* __restrict__ gamma,
                              const float* __restrict__ beta,
                              float* __restrict__ scsh) {
  int j = threadIdx.x;
  float mean = stats[j] * (1.f / NN);
  float var = stats[DD + j] * (1.f / NN) - mean * mean;
  float inv = rsqrtf(var + BN_EPS);
  float sc = gamma[j] * inv;
  scsh[j] = sc;
  scsh[DD + j] = beta[j] - mean * sc;
}

// ---------------------------------------------------------------- BN apply + ReLU
__global__ __launch_bounds__(256) void bn_relu_k(float* __restrict__ out,
                                                 const float* __restrict__ scsh) {
  long long i4 = (long long)blockIdx.x * 256 + threadIdx.x;
  int c4 = (int)(i4 & 31);
  f32x4 sc = *(const f32x4*)(scsh + c4 * 4);
  f32x4 sh = *(const f32x4*)(scsh + DD + c4 * 4);
  f32x4 v = *((f32x4*)out + i4);
#pragma unroll
  for (int k = 0; k < 4; ++k) v[k] = fmaxf(v[k] * sc[k] + sh[k], 0.f);
  *((f32x4*)out + i4) = v;
}

// ---------------------------------------------------------------- launch
extern "C" void kernel_launch(void* const* d_in, const int* in_sizes, int n_in,
                              void* d_out, int out_size, void* d_ws, size_t ws_size,
                              hipStream_t stream) {
  const float* x     = (const float*)d_in[0];
  const int*   lei   = (const int*)d_in[1];
  const int*   gei   = (const int*)d_in[2];
  const float* W1    = (const float*)d_in[3];
  const float* W2L   = (const float*)d_in[4];
  const float* W2G   = (const float*)d_in[5];
  const float* gamma = (const float*)d_in[6];
  const float* beta  = (const float*)d_in[7];
  float* out = (float*)d_out;
  char* xb = (char*)d_out;  // bf16 x, row r at byte r*512

  char* w = (char*)d_ws;
  size_t o = 0;
  unsigned short* aggLb = (unsigned short*)(w + o); o += (size_t)NN * DD * 2;  // 25.6MB
  unsigned short* aggGb = (unsigned short*)(w + o); o += (size_t)NN * DD * 2;  // 25.6MB
  unsigned* edata = (unsigned*)(w + o); o += (size_t)2 * EE * 4;               // 8MB
  int* gCnt = (int*)(w + o); size_t zs = o; o += 1024 * 4;
  int* gOff = (int*)(w + o); o += 1028 * 4;
  int* gCur = (int*)(w + o); o += 1024 * 4;
  unsigned short* Bw = (unsigned short*)(w + o); o += (size_t)DD * 384 * 2;
  float* stats = (float*)(w + o); o += 1024;
  float* scsh  = (float*)(w + o); o += 1024;

  hipMemsetAsync(w + zs, 0, 1024 * 4, stream);  // gCnt
  hipMemsetAsync(stats, 0, 1024, stream);

  xcvt_k<<<(NN * DD / 8) / 256, 256, 0, stream>>>(x, xb);
  packB_k<<<(DD * 384) / 256, 256, 0, stream>>>(W1, W2L, W2G, Bw);

  int nbc = (2 * EE + CHUNK - 1) / CHUNK;  // 245
  bhist_k<<<nbc, 256, 0, stream>>>(lei, gei, gCnt);
  bscan_k<<<1, 256, 0, stream>>>(gCnt, gOff, gCur);
  bscat_k<<<nbc, 256, 0, stream>>>(lei, gei, gCur, edata);
  bgather_k<<<NB, 256, 0, stream>>>(xb, gOff, edata, aggLb, aggGb);

  gemm_k<<<(NN + 127) / 128, 256, 0, stream>>>(xb, aggLb, aggGb, Bw, out, stats);
  bn_finalize_k<<<1, 128, 0, stream>>>(stats, gamma, beta, scsh);
  bn_relu_k<<<(NN * DD / 4) / 256, 256, 0, stream>>>(out, scsh);
}

// Round 5
// 202.871 us; speedup vs baseline: 17.3653x; 1.2574x over previous
//
#include <hip/hip_runtime.h>
#include <cstdint>

#define NN 100000
#define DD 128
#define EE 1000000
#define NBK 782         // buckets of 256 rows over 2*NN combined rows
#define SLOT 4096       // fixed edata slot per bucket (mean 2560, max ~2813)
#define CHUNK 8192      // edges per multisplit block
#define BN_EPS 1e-5f

typedef __attribute__((ext_vector_type(4))) float f32x4;
typedef __attribute__((ext_vector_type(8))) short bf16x8;
typedef __attribute__((ext_vector_type(8))) unsigned short u16x8;

__device__ __forceinline__ unsigned short f2bf(float f) {
  union { float f; unsigned u; } c; c.f = f;
  unsigned u = c.u;
  return (unsigned short)((u + 0x7FFFu + ((u >> 16) & 1u)) >> 16);  // RNE
}
__device__ __forceinline__ float bf2f(unsigned short h) {
  union { unsigned u; float f; } c; c.u = ((unsigned)h) << 16;
  return c.f;
}
__device__ __forceinline__ void gld16(const void* g, void* l) {
  __builtin_amdgcn_global_load_lds(
      (const __attribute__((address_space(1))) unsigned int*)g,
      (__attribute__((address_space(3))) unsigned int*)l, 16, 0, 0);
}

// ---------------------------------------------------------------- x -> bf16 (even 256B half of each 512B out row)
__global__ __launch_bounds__(256) void xcvt_k(const float* __restrict__ x,
                                              char* __restrict__ xb) {
  int i8 = blockIdx.x * 256 + threadIdx.x;  // 1.6M exact
  int row = i8 >> 4, c = i8 & 15;
  const float* src = x + (size_t)row * DD + c * 8;
  f32x4 v0 = *(const f32x4*)src;
  f32x4 v1 = *(const f32x4*)(src + 4);
  u16x8 h;
  h[0] = f2bf(v0[0]); h[1] = f2bf(v0[1]); h[2] = f2bf(v0[2]); h[3] = f2bf(v0[3]);
  h[4] = f2bf(v1[0]); h[5] = f2bf(v1[1]); h[6] = f2bf(v1[2]); h[7] = f2bf(v1[3]);
  *(u16x8*)(xb + (size_t)row * 512 + c * 16) = h;
}

// ---------------------------------------------------------------- pack B [128][384] bf16
__global__ __launch_bounds__(256) void packB_k(
    const float* __restrict__ W1, const float* __restrict__ W2L,
    const float* __restrict__ W2G, unsigned short* __restrict__ Bw) {
  int t = blockIdx.x * 256 + threadIdx.x;
  int j = t / 384, k = t - j * 384;
  const float* W = (k < DD) ? W1 : ((k < 2 * DD) ? W2L : W2G);
  Bw[t] = f2bf(W[j * DD + (k & (DD - 1))]);
}

// ---------------------------------------------------------------- init slot cursors
__global__ __launch_bounds__(256) void init_k(int* __restrict__ gCur) {
  int t = blockIdx.x * 256 + threadIdx.x;  // 1024
  gCur[t] = t * SLOT;
}

// ---------------------------------------------------------------- multisplit scatter into fixed slots
__global__ __launch_bounds__(256) void bscat_k(const int* __restrict__ lei,
                                               const int* __restrict__ gei,
                                               int* __restrict__ gCur,
                                               unsigned* __restrict__ edata) {
  __shared__ int lofs[1025];
  __shared__ int lcur[1024];
  __shared__ int gbase[1024];
  __shared__ unsigned short bid[CHUNK];
  __shared__ unsigned stage[CHUNK];
  __shared__ int wsum[4];
  int t = threadIdx.x;
  int base = blockIdx.x * CHUNK;
  int cnt = 2 * EE - base; if (cnt > CHUNK) cnt = CHUNK;
#pragma unroll
  for (int k = 0; k < 4; ++k) lofs[t * 4 + k] = 0;
  __syncthreads();
#pragma unroll 4
  for (int j = 0; j < CHUNK / 256; ++j) {
    int i = base + j * 256 + t;
    if (i < 2 * EE) {
      int grow = (i < EE) ? lei[i] : (NN + gei[i - EE]);
      atomicAdd(&lofs[grow >> 8], 1);
    }
  }
  __syncthreads();
  int v[4];
#pragma unroll
  for (int k = 0; k < 4; ++k) v[k] = lofs[t * 4 + k];
  int tot = v[0] + v[1] + v[2] + v[3];
  int lane = t & 63, wv = t >> 6;
  int inc = tot;
  for (int d = 1; d < 64; d <<= 1) { int u = __shfl_up(inc, d); if (lane >= d) inc += u; }
  if (lane == 63) wsum[wv] = inc;
  __syncthreads();
  int woff = 0;
#pragma unroll
  for (int w = 0; w < 4; ++w) if (w < wv) woff += wsum[w];
  int run = woff + inc - tot;
#pragma unroll
  for (int k = 0; k < 4; ++k) { lofs[t * 4 + k] = run; lcur[t * 4 + k] = run; run += v[k]; }
  if (t == 0) lofs[1024] = cnt;
  __syncthreads();
#pragma unroll 4
  for (int j = 0; j < CHUNK / 256; ++j) {
    int i = base + j * 256 + t;
    if (i < 2 * EE) {
      int grow, col;
      if (i < EE) { grow = lei[i]; col = lei[EE + i]; }
      else        { grow = NN + gei[i - EE]; col = gei[i]; }
      int b = grow >> 8;
      int pos = atomicAdd(&lcur[b], 1);
      stage[pos] = (unsigned)col | ((unsigned)(grow & 255) << 24);
      bid[pos] = (unsigned short)b;
    }
  }
  __syncthreads();
#pragma unroll
  for (int k = 0; k < 4; ++k) {
    int b = t * 4 + k;
    int c = lofs[b + 1] - lofs[b];
    if (c > 0) gbase[b] = atomicAdd(&gCur[b], c);
  }
  __syncthreads();
  for (int i = t; i < cnt; i += 256) {
    int b = bid[i];
    edata[gbase[b] + (i - lofs[b])] = stage[i];
  }
}

// ---------------------------------------------------------------- per-half-bucket LDS CSR + gather
// block h: bucket b=h>>1, rows [b*256 + (h&1)*128, +128)
__global__ __launch_bounds__(256) void bgather_k(const char* __restrict__ xb,
                                                 const int* __restrict__ gCur,
                                                 const unsigned* __restrict__ edata,
                                                 unsigned short* __restrict__ aggLb,
                                                 char* __restrict__ outD) {
  __shared__ int rowOff[129];
  __shared__ int rowCur[128];
  __shared__ unsigned colS[2048];
  __shared__ int wsum1;
  int t = threadIdx.x;
  int h = blockIdx.x, b = h >> 1, half = h & 1;
  int s0 = b * SLOT;
  int cnt = gCur[b] - s0;
  if (t < 128) rowCur[t] = 0;
  __syncthreads();
  for (int i = t; i < cnt; i += 256) {
    unsigned e = edata[s0 + i];
    unsigned r8 = e >> 24;
    if ((int)(r8 >> 7) == half) atomicAdd(&rowCur[r8 & 127], 1);
  }
  __syncthreads();
  int v = 0, inc = 0;
  if (t < 128) {  // waves 0,1 fully active
    v = rowCur[t];
    inc = v;
    int lane = t & 63;
    for (int d = 1; d < 64; d <<= 1) { int u = __shfl_up(inc, d); if (lane >= d) inc += u; }
    if (t == 63) wsum1 = inc;
  }
  __syncthreads();
  if (t < 128) {
    int excl = inc - v + ((t >> 6) ? wsum1 : 0);
    rowOff[t] = excl;
    if (t == 127) rowOff[128] = excl + v;
    rowCur[t] = excl;
  }
  __syncthreads();
  for (int i = t; i < cnt; i += 256) {
    unsigned e = edata[s0 + i];
    unsigned r8 = e >> 24;
    if ((int)(r8 >> 7) == half) {
      int pos = atomicAdd(&rowCur[r8 & 127], 1);
      if (pos < 2048) colS[pos] = e & 0xFFFFFFu;
    }
  }
  __syncthreads();
  int g16 = t >> 4, lane16 = t & 15;
  int rowsbase = b * 256 + half * 128;
  for (int r = g16; r < 128; r += 16) {
    int grow = rowsbase + r;
    if (grow >= 2 * NN) break;
    int e0 = rowOff[r], e1 = rowOff[r + 1];
    float a[8] = {0.f, 0.f, 0.f, 0.f, 0.f, 0.f, 0.f, 0.f};
    for (int i = e0; i < e1; ++i) {
      unsigned col = colS[i];
      u16x8 x8 = *(const u16x8*)(xb + (size_t)col * 512 + lane16 * 16);
#pragma unroll
      for (int j = 0; j < 8; ++j) a[j] += bf2f(x8[j]);
    }
    u16x8 hv;
#pragma unroll
    for (int j = 0; j < 8; ++j) hv[j] = f2bf(a[j]);
    if (grow < NN)
      *(u16x8*)(aggLb + (size_t)grow * DD + lane16 * 8) = hv;
    else
      *(u16x8*)(outD + (size_t)(grow - NN) * 512 + 256 + lane16 * 16) = hv;
  }
}

// ---------------------------------------------------------------- GEMM (bf16 A via global_load_lds, dbuf, swizzled)
__global__ __launch_bounds__(256, 2) void gemm_k(
    const char* __restrict__ xb, const unsigned short* __restrict__ aggLb,
    const unsigned short* __restrict__ Bw,
    float* __restrict__ out, float* __restrict__ stats) {
  __shared__ unsigned short Asm[2][128 * 64];
  __shared__ unsigned short Bsm[2][128 * 64];
  __shared__ float red[4][256];
  int t = threadIdx.x, wave = t >> 6, lane = t & 63;
  int row0 = blockIdx.x * 128;

  f32x4 acc[2][8];
#pragma unroll
  for (int mi = 0; mi < 2; ++mi)
#pragma unroll
    for (int ni = 0; ni < 8; ++ni) acc[mi][ni] = (f32x4){0.f, 0.f, 0.f, 0.f};

  auto STAGE = [&](int s, int b) {
#pragma unroll
    for (int i = 0; i < 4; ++i) {
      int flat = t + i * 256, r = flat >> 3, c = flat & 7;
      int rr = row0 + r; rr = (rr < NN) ? rr : (NN - 1);
      const char* src;
      if (s < 2)      src = xb + (size_t)rr * 512 + (s & 1) * 128 + ((c ^ (r & 7)) << 4);
      else if (s < 4) src = (const char*)aggLb + (size_t)rr * 256 + (s & 1) * 128 + ((c ^ (r & 7)) << 4);
      else            src = xb + (size_t)rr * 512 + 256 + (s & 1) * 128 + ((c ^ (r & 7)) << 4);
      gld16(src, &Asm[b][(size_t)(i * 256 + wave * 64) * 8]);
    }
#pragma unroll
    for (int i = 0; i < 4; ++i) {
      int flat = t + i * 256, n = flat >> 3, c = flat & 7;
      const char* src = (const char*)Bw + (size_t)n * 768 + s * 128 + ((c ^ (n & 7)) << 4);
      gld16(src, &Bsm[b][(size_t)(i * 256 + wave * 64) * 8]);
    }
  };

  auto COMPUTE = [&](int b) {
    int mr = lane & 15, kq = lane >> 4;
#pragma unroll
    for (int ki = 0; ki < 2; ++ki) {
      int kg = ki * 4 + kq;
      int r0 = wave * 32 + mr, r1 = r0 + 16;
      bf16x8 a0 = *(const bf16x8*)&Asm[b][((size_t)r0 * 8 + (kg ^ (r0 & 7))) * 8];
      bf16x8 a1 = *(const bf16x8*)&Asm[b][((size_t)r1 * 8 + (kg ^ (r1 & 7))) * 8];
#pragma unroll
      for (int ni = 0; ni < 8; ++ni) {
        int nr = ni * 16 + mr;
        bf16x8 bb = *(const bf16x8*)&Bsm[b][((size_t)nr * 8 + (kg ^ (nr & 7))) * 8];
        acc[0][ni] = __builtin_amdgcn_mfma_f32_16x16x32_bf16(a0, bb, acc[0][ni], 0, 0, 0);
        acc[1][ni] = __builtin_amdgcn_mfma_f32_16x16x32_bf16(a1, bb, acc[1][ni], 0, 0, 0);
      }
    }
  };

  STAGE(0, 0);
  __syncthreads();
#pragma unroll
  for (int s = 0; s < 6; ++s) {
    int b = s & 1;
    if (s < 5) STAGE(s + 1, b ^ 1);
    COMPUTE(b);
    __syncthreads();
  }

  int colbase = lane & 15, rbase = (lane >> 4) * 4;
#pragma unroll
  for (int ni = 0; ni < 8; ++ni) {
    int col = ni * 16 + colbase;
    float s = 0.f, q = 0.f;
#pragma unroll
    for (int mi = 0; mi < 2; ++mi)
#pragma unroll
      for (int r = 0; r < 4; ++r) {
        int row = row0 + wave * 32 + mi * 16 + rbase + r;
        float v = acc[mi][ni][r];
        if (row < NN) {
          out[(size_t)row * DD + col] = v;
          s += v; q += v * v;
        }
      }
    s += __shfl_xor(s, 16); s += __shfl_xor(s, 32);
    q += __shfl_xor(q, 16); q += __shfl_xor(q, 32);
    if (lane < 16) { red[wave][col] = s; red[wave][128 + col] = q; }
  }
  __syncthreads();
  float v = red[0][t & 255] + red[1][t & 255] + red[2][t & 255] + red[3][t & 255];
  atomicAdd(&stats[t & 255], v);
}

// ---------------------------------------------------------------- BN finalize
__global__ void bn_finalize_k(const float* __restrict__ stats,
                              const float* __restrict__ gamma,
                              const float* __restrict__ beta,
                              float* __restrict__ scsh) {
  int j = threadIdx.x;
  float mean = stats[j] * (1.f / NN);
  float var = stats[DD + j] * (1.f / NN) - mean * mean;
  float inv = rsqrtf(var + BN_EPS);
  float sc = gamma[j] * inv;
  scsh[j] = sc;
  scsh[DD + j] = beta[j] - mean * sc;
}

// ---------------------------------------------------------------- BN apply + ReLU
__global__ __launch_bounds__(256) void bn_relu_k(float* __restrict__ out,
                                                 const float* __restrict__ scsh) {
  long long i4 = (long long)blockIdx.x * 256 + threadIdx.x;
  int c4 = (int)(i4 & 31);
  f32x4 sc = *(const f32x4*)(scsh + c4 * 4);
  f32x4 sh = *(const f32x4*)(scsh + DD + c4 * 4);
  f32x4 v = *((f32x4*)out + i4);
#pragma unroll
  for (int k = 0; k < 4; ++k) v[k] = fmaxf(v[k] * sc[k] + sh[k], 0.f);
  *((f32x4*)out + i4) = v;
}

// ---------------------------------------------------------------- launch
extern "C" void kernel_launch(void* const* d_in, const int* in_sizes, int n_in,
                              void* d_out, int out_size, void* d_ws, size_t ws_size,
                              hipStream_t stream) {
  const float* x     = (const float*)d_in[0];
  const int*   lei   = (const int*)d_in[1];
  const int*   gei   = (const int*)d_in[2];
  const float* W1    = (const float*)d_in[3];
  const float* W2L   = (const float*)d_in[4];
  const float* W2G   = (const float*)d_in[5];
  const float* gamma = (const float*)d_in[6];
  const float* beta  = (const float*)d_in[7];
  float* out = (float*)d_out;
  char* xb = (char*)d_out;  // bf16 x in even 256B halves; aggG in odd halves

  char* w = (char*)d_ws;
  size_t o = 0;
  unsigned short* aggLb = (unsigned short*)(w + o); o += (size_t)NN * DD * 2;  // 25.6MB
  unsigned* edata = (unsigned*)(w + o); o += (size_t)NBK * SLOT * 4;           // 12.8MB
  int* gCur = (int*)(w + o); o += 1024 * 4;
  unsigned short* Bw = (unsigned short*)(w + o); o += (size_t)DD * 384 * 2;    // 96KB
  float* stats = (float*)(w + o); o += 1024;
  float* scsh  = (float*)(w + o); o += 1024;

  hipMemsetAsync(stats, 0, 1024, stream);

  xcvt_k<<<(NN * DD / 8) / 256, 256, 0, stream>>>(x, xb);
  packB_k<<<(DD * 384) / 256, 256, 0, stream>>>(W1, W2L, W2G, Bw);
  init_k<<<4, 256, 0, stream>>>(gCur);

  int nbc = (2 * EE + CHUNK - 1) / CHUNK;  // 245
  bscat_k<<<nbc, 256, 0, stream>>>(lei, gei, gCur, edata);
  bgather_k<<<2 * NBK, 256, 0, stream>>>(xb, gCur, edata, aggLb, xb);

  gemm_k<<<(NN + 127) / 128, 256, 0, stream>>>(xb, aggLb, Bw, out, stats);
  bn_finalize_k<<<1, 128, 0, stream>>>(stats, gamma, beta, scsh);
  bn_relu_k<<<(NN * DD / 4) / 256, 256, 0, stream>>>(out, scsh);
}